// Round 5
// baseline (4495.390 us; speedup 1.0000x reference)
//
#include <hip/hip_runtime.h>
#include <cstdint>

// Problem constants (from reference)
#define VN 100000   // vocab
#define DD 128      // D
#define BB 512      // batch
#define LL 20       // session length
#define TT 20       // time steps
#define HH 32       // H
#define CC 33       // C = H+1
#define NC (HH*CC)  // 1056

typedef unsigned int u32;

#define DEV static __device__ __forceinline__

DEV float tanh_fast(float x){ float e=__expf(2.f*x); return 1.f - 2.f/(e+1.f); }

// broadcast a lane's value wave-wide via v_readlane -> SGPR (folds into v_fma scalar src)
DEV float rdlane(float v, int l){
  return __int_as_float(__builtin_amdgcn_readlane(__float_as_int(v), l));
}

// Remat-blocker: after an asm that MAY MODIFY the value, reloading it from
// global memory is no longer a legal substitute -> the value must live in a
// register. (Rounds 1-4: loads of w2 via __restrict__ const kernarg are
// treated as rematerializable invariant loads and get sunk into the loop —
// VGPR stuck at 128, FETCH 2.3-5.9 GB of per-substage re-reads. waves_per_eu
// was honored for occupancy but could not forbid the remat.)
#define PINF(x)  asm volatile("" : "+v"(x))
#define PIN4(v)  asm volatile("" : "+v"(v.x), "+v"(v.y), "+v"(v.z), "+v"(v.w))

// ================= K1: fused knots + CDE RK4 scan ==========================
//   wa0..wa31 : row A = w2[h*33+2q]          fully cached (128 f, PINNED)
//   wb0..wb7  : row B = w2[h*33+2q+1][0:32]  cached (32 f, PINNED)
//   rest of row B (96 f) streamed per substage; its footprint (512 distinct
//   rows x 384 B = 196 KB, shared by all blocks) is L2-resident.
// 512 threads, G=2, 256 blocks (1 block/CU), 2 waves/EU -> 256-VGPR budget;
// pinned live set ~200 regs.
__global__ __launch_bounds__(512)
__attribute__((amdgpu_waves_per_eu(2, 2)))
void k_cde(
    const float* __restrict__ emb, const int* __restrict__ eids,
    const float* __restrict__ times,
    const float* __restrict__ red_w, const float* __restrict__ red_b,
    const float* __restrict__ w1, const float* __restrict__ b1,
    const float* __restrict__ w2, const float* __restrict__ b2,
    const float* __restrict__ iw, const float* __restrict__ ib,
    const float* __restrict__ rw, const float* __restrict__ rb,
    float* __restrict__ te){
  __shared__ float s_u[40*DD + 32*129];  // phase1: er(5120)|rw(4128); phase2: w1 (128*33)
  __shared__ float s_X[2*TT*CC];         // [g][t][c], persistent
  __shared__ float s_b1[DD];
  __shared__ float s_h1[2*DD];           // [g][j]
  __shared__ float s_z[64], s_zs[64], s_ks[64], s_kp[64], s_kt[64];
  __shared__ float s_dx[2*CC];
  const int t = threadIdx.x;
  const int b0 = blockIdx.x*2;
  const int lane = t & 63;
  const int wv = t >> 6;                 // wave 0..7
  const int h  = t >> 4;                 // 0..31
  const int q  = t & 15;                 // 0..15
  float* s_er = s_u;
  float* s_rw = s_u + 40*DD;             // phase1, rows padded to 129
  float* s_w1 = s_u;                     // phase2 alias, [j*33+h]

  // ---- phase 1: knots X[g][t][:] ----
  for (int i=t;i<HH*DD;i+=512){ int hh=i>>7, d=i&127; s_rw[hh*129+d]=red_w[i]; }
  if (t<40){ int g=t/TT, tt2=t%TT; s_X[(g*TT+tt2)*CC]=times[(b0+g)*TT+tt2]; }
  for (int pi=t;pi<40*DD;pi+=512){ int r=pi>>7, e=pi&127;
      s_er[pi]=emb[(size_t)eids[b0*TT+r]*DD+e]; }
  __syncthreads();
  for (int task=t; task<40*HH; task+=512){   // 512%32==0 -> shuffle groups aligned
    int r=task>>5, hh=task&31;
    const float* wr=s_rw+hh*129;
    const float* er=s_er+(size_t)r*DD;
    float acc=red_b[hh];
    #pragma unroll 16
    for(int e=0;e<DD;e++) acc += er[e]*wr[e];
    float ssq=acc*acc;
    #pragma unroll
    for(int o=16;o>0;o>>=1) ssq+=__shfl_xor(ssq,o,32);
    s_X[r*CC+1+hh]=acc/(sqrtf(ssq)+1e-12f);   // fode = l2n(...) into X[...,1+h]
  }
  __syncthreads();                            // fode readers done; union free

  // ---- w2 -> named registers, PINNED so the loads cannot be sunk/remat'd ----
  const float4* ra4 = (const float4*)(w2 + (size_t)(h*CC + 2*q)*DD);  // row A
  const float4* rb4 = ra4 + 32;                                        // row B
  float4 wa0 =ra4[0],  wa1 =ra4[1],  wa2 =ra4[2],  wa3 =ra4[3],
         wa4 =ra4[4],  wa5 =ra4[5],  wa6 =ra4[6],  wa7 =ra4[7],
         wa8 =ra4[8],  wa9 =ra4[9],  wa10=ra4[10], wa11=ra4[11],
         wa12=ra4[12], wa13=ra4[13], wa14=ra4[14], wa15=ra4[15],
         wa16=ra4[16], wa17=ra4[17], wa18=ra4[18], wa19=ra4[19],
         wa20=ra4[20], wa21=ra4[21], wa22=ra4[22], wa23=ra4[23],
         wa24=ra4[24], wa25=ra4[25], wa26=ra4[26], wa27=ra4[27],
         wa28=ra4[28], wa29=ra4[29], wa30=ra4[30], wa31=ra4[31];
  float4 wb0=rb4[0], wb1=rb4[1], wb2=rb4[2], wb3=rb4[3],
         wb4v=rb4[4], wb5=rb4[5], wb6=rb4[6], wb7=rb4[7];
  PIN4(wa0);  PIN4(wa1);  PIN4(wa2);  PIN4(wa3);
  PIN4(wa4);  PIN4(wa5);  PIN4(wa6);  PIN4(wa7);
  PIN4(wa8);  PIN4(wa9);  PIN4(wa10); PIN4(wa11);
  PIN4(wa12); PIN4(wa13); PIN4(wa14); PIN4(wa15);
  PIN4(wa16); PIN4(wa17); PIN4(wa18); PIN4(wa19);
  PIN4(wa20); PIN4(wa21); PIN4(wa22); PIN4(wa23);
  PIN4(wa24); PIN4(wa25); PIN4(wa26); PIN4(wa27);
  PIN4(wa28); PIN4(wa29); PIN4(wa30); PIN4(wa31);
  PIN4(wb0);  PIN4(wb1);  PIN4(wb2);  PIN4(wb3);
  PIN4(wb4v); PIN4(wb5);  PIN4(wb6);  PIN4(wb7);
  float b2A = b2[h*CC+2*q];
  float b2B = b2[h*CC+2*q+1];
  PINF(b2A); PINF(b2B);
  // tail rows n=(4wv+r)*33+32: lane holds elems [lane], [64+lane] (pinned scalars)
  float wt0,wt1,wt2,wt3,wt4,wt5,wt6,wt7, bt0,bt1,bt2,bt3;
  { const float* tr=w2+(size_t)((4*wv+0)*CC+32)*DD; wt0=tr[lane]; wt1=tr[64+lane]; bt0=b2[(4*wv+0)*CC+32]; }
  { const float* tr=w2+(size_t)((4*wv+1)*CC+32)*DD; wt2=tr[lane]; wt3=tr[64+lane]; bt1=b2[(4*wv+1)*CC+32]; }
  { const float* tr=w2+(size_t)((4*wv+2)*CC+32)*DD; wt4=tr[lane]; wt5=tr[64+lane]; bt2=b2[(4*wv+2)*CC+32]; }
  { const float* tr=w2+(size_t)((4*wv+3)*CC+32)*DD; wt6=tr[lane]; wt7=tr[64+lane]; bt3=b2[(4*wv+3)*CC+32]; }
  PINF(wt0); PINF(wt1); PINF(wt2); PINF(wt3);
  PINF(wt4); PINF(wt5); PINF(wt6); PINF(wt7);
  PINF(bt0); PINF(bt1); PINF(bt2); PINF(bt3);

  // ---- phase 2 weights: w1 (stride 33, conflict-free b32 reads), b1 ----
  for (int i=t;i<DD*HH;i+=512){ int j=i>>5, hh=i&31; s_w1[j*33+hh]=w1[i]; }
  if (t<DD) s_b1[t]=b1[t];
  // ---- z0 = X[:,0] @ init_w.T + init_b ----
  if (t<64){
    int g=t>>5, hh=t&31;
    float acc=ib[hh];
    const float* x0=s_X+(size_t)(g*TT)*CC;
    #pragma unroll
    for(int c=0;c<CC;c++) acc += x0[c]*iw[hh*CC+c];
    s_z[t]=acc; s_zs[t]=acc;
  }
  __syncthreads();   // w1/b1/z0 ready

// per-element MAC: broadcast h1[g][E] via readlane (constant lane after expansion)
#define EL(E, WAe, WBe) { \
  const float s0_ = ((E)<64)? rdlane(h00,(E)&63) : rdlane(h01,(E)&63); \
  const float s1_ = ((E)<64)? rdlane(h10,(E)&63) : rdlane(h11,(E)&63); \
  aA0 += s0_*(WAe); aA1 += s1_*(WAe); \
  aB0 += s0_*(WBe); aB1 += s1_*(WBe); }
#define QC(J, WAV, WBV) \
  EL(4*(J)+0, (WAV).x, (WBV).x) \
  EL(4*(J)+1, (WAV).y, (WBV).y) \
  EL(4*(J)+2, (WAV).z, (WBV).z) \
  EL(4*(J)+3, (WAV).w, (WBV).w)
#define QS(J, WAV) { const float4 bv_ = rb4[J]; \
  EL(4*(J)+0, (WAV).x, bv_.x) \
  EL(4*(J)+1, (WAV).y, bv_.y) \
  EL(4*(J)+2, (WAV).z, bv_.z) \
  EL(4*(J)+3, (WAV).w, bv_.w) }

  for (int step=0; step<TT-1; step++){
    if (t<2*CC){ int g=t/CC, c=t-g*CC;
      s_dx[t]=s_X[(g*TT+step+1)*CC+c]-s_X[(g*TT+step)*CC+c]; }
    for (int s=0;s<4;s++){
      // ---- stage A: h1 = relu(zs @ w1.T + b1) ----
      if (t<256){
        const int g=t>>7, j=t&127, gb=(t>>7)*32;
        float zsv=s_zs[lane];
        float acc=s_b1[j];
        const float* wj=s_w1+j*33;
        #pragma unroll
        for(int hh=0;hh<HH;hh++) acc += rdlane(zsv, gb+hh)*wj[hh];
        s_h1[g*DD+j]=fmaxf(acc,0.f);
      }
      __syncthreads();   // sync_A: h1 (and s_dx) ready
      {
        const float h00=s_h1[lane],    h01=s_h1[64+lane];     // g=0
        const float h10=s_h1[DD+lane], h11=s_h1[DD+64+lane];  // g=1
        float aA0=b2A, aA1=b2A, aB0=b2B, aB1=b2B;
        QC(0,wa0,wb0)   QC(1,wa1,wb1)   QC(2,wa2,wb2)   QC(3,wa3,wb3)
        QC(4,wa4,wb4v)  QC(5,wa5,wb5)   QC(6,wa6,wb6)   QC(7,wa7,wb7)
        QS(8,wa8)   QS(9,wa9)   QS(10,wa10) QS(11,wa11)
        QS(12,wa12) QS(13,wa13) QS(14,wa14) QS(15,wa15)
        QS(16,wa16) QS(17,wa17) QS(18,wa18) QS(19,wa19)
        QS(20,wa20) QS(21,wa21) QS(22,wa22) QS(23,wa23)
        QS(24,wa24) QS(25,wa25) QS(26,wa26) QS(27,wa27)
        QS(28,wa28) QS(29,wa29) QS(30,wa30) QS(31,wa31)
        // main-row k contributions; reduce over q within each 16-group (one h)
        float pk0 = tanh_fast(aA0)*s_dx[2*q]    + tanh_fast(aB0)*s_dx[2*q+1];
        float pk1 = tanh_fast(aA1)*s_dx[CC+2*q] + tanh_fast(aB1)*s_dx[CC+2*q+1];
        #pragma unroll
        for (int o=8;o>0;o>>=1){ pk0+=__shfl_xor(pk0,o,16); pk1+=__shfl_xor(pk1,o,16); }
        if (q==0){ s_kp[h]=pk0; s_kp[32+h]=pk1; }
        // tail rows (c=32): lane-parallel partials, full-wave butterfly
        float p0=wt0*h00+wt1*h01;
        float p1=wt0*h10+wt1*h11;
        float p2=wt2*h00+wt3*h01;
        float p3=wt2*h10+wt3*h11;
        float p4=wt4*h00+wt5*h01;
        float p5=wt4*h10+wt5*h11;
        float p6=wt6*h00+wt7*h01;
        float p7=wt6*h10+wt7*h11;
        #pragma unroll
        for (int o=1;o<64;o<<=1){
          p0+=__shfl_xor(p0,o,64); p1+=__shfl_xor(p1,o,64);
          p2+=__shfl_xor(p2,o,64); p3+=__shfl_xor(p3,o,64);
          p4+=__shfl_xor(p4,o,64); p5+=__shfl_xor(p5,o,64);
          p6+=__shfl_xor(p6,o,64); p7+=__shfl_xor(p7,o,64);
        }
        if (lane==0){
          float dt0=s_dx[32], dt1=s_dx[CC+32];
          s_kt[4*wv+0]   =tanh_fast(p0+bt0)*dt0;
          s_kt[32+4*wv+0]=tanh_fast(p1+bt0)*dt1;
          s_kt[4*wv+1]   =tanh_fast(p2+bt1)*dt0;
          s_kt[32+4*wv+1]=tanh_fast(p3+bt1)*dt1;
          s_kt[4*wv+2]   =tanh_fast(p4+bt2)*dt0;
          s_kt[32+4*wv+2]=tanh_fast(p5+bt2)*dt1;
          s_kt[4*wv+3]   =tanh_fast(p6+bt3)*dt0;
          s_kt[32+4*wv+3]=tanh_fast(p7+bt3)*dt1;
        }
      }
      __syncthreads();   // sync_B: kp/kt ready
      if (t<64){         // RK4 bookkeeping: one thread per (g,h)
        float k=s_kp[t]+s_kt[t];
        float zv=s_z[t];
        if(s==0){ s_ks[t]=k;        s_zs[t]=zv+0.5f*k; }
        else if(s==1){ s_ks[t]+=2.f*k; s_zs[t]=zv+0.5f*k; }
        else if(s==2){ s_ks[t]+=2.f*k; s_zs[t]=zv+k; }
        else { float zn=zv+(s_ks[t]+k)*(1.f/6.f); s_z[t]=zn; s_zs[t]=zn; }
      }
      __syncthreads();   // sync_C: zs ready for next substage
    }
  }
#undef EL
#undef QC
#undef QS
  // ---- epilogue: time_embeds = zT @ rec_w.T + rec_b ----
  if (t<256){
    const int g=t>>7, d=t&127;
    float acc=rb[d];
    const float* zz=s_z+g*HH;
    const float4* rv=(const float4*)(rw + (size_t)d*HH);
    #pragma unroll
    for(int jj=0;jj<8;jj++){
      float4 vv=rv[jj];
      acc += zz[4*jj]*vv.x + zz[4*jj+1]*vv.y + zz[4*jj+2]*vv.z + zz[4*jj+3]*vv.w;
    }
    te[(size_t)(b0+g)*DD+d]=acc;
  }
}

// ================= K2: attention readout + sr (featn recomputed) ===========
__global__ __launch_bounds__(128) void k_attn(
    const float* __restrict__ emb, const int* __restrict__ iid,
    const int* __restrict__ last_nodes,
    const float* __restrict__ fcu_w, const float* __restrict__ fcv_w,
    const float* __restrict__ fcv_b, const float* __restrict__ fce_w,
    const float* __restrict__ fcsr_w,
    const float* __restrict__ te, float* __restrict__ sr){
  __shared__ float s_fn[LL*DD];      // featn tile = x/||x||
  __shared__ float s_inv[LL];
  __shared__ float s_e[LL], s_alpha[LL], s_red[2], s_sg[DD], s_fl[DD];
  const int t=threadIdx.x, b=blockIdx.x;
  for(int p=t;p<LL*DD;p+=128){
    int r=p>>7, e=p&127;
    s_fn[p]=emb[(size_t)iid[b*LL+r]*DD+e];
  }
  __syncthreads();
  { int w=t>>6, lane=t&63;
    for(int r=w;r<LL;r+=2){
      float a=s_fn[r*DD+lane], c=s_fn[r*DD+lane+64];
      float s=a*a+c*c;
      #pragma unroll
      for(int o=32;o>0;o>>=1) s+=__shfl_xor(s,o,64);
      if(lane==0) s_inv[r]=1.f/sqrtf(s);
    }
  }
  __syncthreads();
  for(int p=t;p<LL*DD;p+=128) s_fn[p]*=s_inv[p>>7];
  __syncthreads();
  int lr=last_nodes[b]-b*LL; if(lr<0||lr>=LL) lr=LL-1;   // == L-1 by construction
  s_fl[t]=s_fn[lr*DD+t];
  __syncthreads();
  float fv;
  {
    float acc=fcv_b[t];
    const float* wv=fcv_w + t*DD;
    #pragma unroll 8
    for(int j=0;j<DD;j++) acc += s_fl[j]*wv[j];
    fv=acc;
  }
  const float fce=fce_w[t];
  const float* wu=fcu_w + t*DD;
  for(int n=0;n<LL;n++){
    float fu=0.f;
    #pragma unroll 8
    for(int j=0;j<DD;j++) fu += s_fn[n*DD+j]*wu[j];
    float sv = fce/(1.f+__expf(-(fu+fv)));   // sigmoid * fce_w[d]
    #pragma unroll
    for(int o=32;o>0;o>>=1) sv += __shfl_xor(sv,o,64);
    if((t&63)==0) s_red[t>>6]=sv;
    __syncthreads();
    if(t==0) s_e[n]=s_red[0]+s_red[1];
    __syncthreads();
  }
  if(t<64){ // softmax over the 20 session nodes
    float ev=(t<LL)? s_e[t] : -1e30f;
    float m=ev;
    #pragma unroll
    for(int o=32;o>0;o>>=1) m=fmaxf(m,__shfl_xor(m,o,64));
    float ex=(t<LL)? __expf(ev-m):0.f;
    float ssum=ex;
    #pragma unroll
    for(int o=32;o>0;o>>=1) ssum+=__shfl_xor(ssum,o,64);
    if(t<LL) s_alpha[t]=ex/ssum;
  }
  __syncthreads();
  float sg=0.f;
  for(int n=0;n<LL;n++) sg += s_alpha[n]*s_fn[n*DD+t];
  s_sg[t]=sg;
  __syncthreads();
  // sr = l2n([sr_l, sr_g] @ fcsr_w.T + te)
  float pre=te[(size_t)b*DD+t];
  const float* wsr=fcsr_w + t*2*DD;
  #pragma unroll 8
  for(int j=0;j<DD;j++) pre += s_fl[j]*wsr[j];
  #pragma unroll 8
  for(int j=0;j<DD;j++) pre += s_sg[j]*wsr[DD+j];
  float ss=pre*pre;
  #pragma unroll
  for(int o=32;o>0;o>>=1) ss+=__shfl_xor(ss,o,64);
  if((t&63)==0) s_red[t>>6]=ss;
  __syncthreads();
  float tot=s_red[0]+s_red[1];
  sr[(size_t)b*DD+t]=pre/(sqrtf(tot)+1e-12f);
}

// ================= K3: logits (f32 out), inline emb-row norm ===============
// Same remat hazard as k_cde: er[128] must persist across the 256-iter b-loop,
// but invariant-load remat re-streams the emb row from L1/L2 every iteration.
// Fix: 32 named float4 + "+v" pins + waves_per_eu(2,2).
__global__ __launch_bounds__(256, 2)
__attribute__((amdgpu_waves_per_eu(2, 2)))
void k_logits(
    const float* __restrict__ emb, const float* __restrict__ srr,
    float* __restrict__ out){
  const int v=blockIdx.x*256+threadIdx.x;
  if(v>=VN) return;
  const int bstart=blockIdx.y*256;
  const float4* ev=(const float4*)emb + (size_t)v*32;
#define ELD(i) float4 e##i = ev[i]; PIN4(e##i);
  ELD(0)  ELD(1)  ELD(2)  ELD(3)  ELD(4)  ELD(5)  ELD(6)  ELD(7)
  ELD(8)  ELD(9)  ELD(10) ELD(11) ELD(12) ELD(13) ELD(14) ELD(15)
  ELD(16) ELD(17) ELD(18) ELD(19) ELD(20) ELD(21) ELD(22) ELD(23)
  ELD(24) ELD(25) ELD(26) ELD(27) ELD(28) ELD(29) ELD(30) ELD(31)
#undef ELD
  float nrm=0.f;
#define ENRM(i) nrm += e##i.x*e##i.x + e##i.y*e##i.y + e##i.z*e##i.z + e##i.w*e##i.w;
  ENRM(0)  ENRM(1)  ENRM(2)  ENRM(3)  ENRM(4)  ENRM(5)  ENRM(6)  ENRM(7)
  ENRM(8)  ENRM(9)  ENRM(10) ENRM(11) ENRM(12) ENRM(13) ENRM(14) ENRM(15)
  ENRM(16) ENRM(17) ENRM(18) ENRM(19) ENRM(20) ENRM(21) ENRM(22) ENRM(23)
  ENRM(24) ENRM(25) ENRM(26) ENRM(27) ENRM(28) ENRM(29) ENRM(30) ENRM(31)
#undef ENRM
  const float rn=12.f/(sqrtf(nrm)+1e-12f);
  for(int b=bstart;b<bstart+256;b++){
    const float4* s4=(const float4*)(srr+(size_t)b*DD);  // wave-uniform -> scalar loads
    float acc=0.f;
#define EDOT(i) { float4 sv_=s4[i]; \
    acc += e##i.x*sv_.x + e##i.y*sv_.y + e##i.z*sv_.z + e##i.w*sv_.w; }
    EDOT(0)  EDOT(1)  EDOT(2)  EDOT(3)  EDOT(4)  EDOT(5)  EDOT(6)  EDOT(7)
    EDOT(8)  EDOT(9)  EDOT(10) EDOT(11) EDOT(12) EDOT(13) EDOT(14) EDOT(15)
    EDOT(16) EDOT(17) EDOT(18) EDOT(19) EDOT(20) EDOT(21) EDOT(22) EDOT(23)
    EDOT(24) EDOT(25) EDOT(26) EDOT(27) EDOT(28) EDOT(29) EDOT(30) EDOT(31)
#undef EDOT
    out[(size_t)b*VN+v]=acc*rn;
  }
}

// ================= K4: per-row logsumexp over V (online, f32) ==============
__global__ __launch_bounds__(256) void k_lse(const float* __restrict__ out,
                                             float* __restrict__ lse){
  const int b=blockIdx.x, t=threadIdx.x;
  const float4* rp=(const float4*)(out + (size_t)b*VN);
  float m=-1e30f, s=0.f;
  for(int i=t;i<VN/4;i+=256){
    float4 x=rp[i];
    float mx=fmaxf(fmaxf(x.x,x.y),fmaxf(x.z,x.w));
    if(mx>m){ s=s*__expf(m-mx); m=mx; }
    s += __expf(x.x-m)+__expf(x.y-m)+__expf(x.z-m)+__expf(x.w-m);
  }
  __shared__ float sm[256], ssb[256];
  sm[t]=m; ssb[t]=s;
  __syncthreads();
  for(int o=128;o>0;o>>=1){
    if(t<o){
      float m1=sm[t], m2=sm[t+o], s1=ssb[t], s2=ssb[t+o];
      float mm=fmaxf(m1,m2);
      sm[t]=mm; ssb[t]=s1*__expf(m1-mm)+s2*__expf(m2-mm);
    }
    __syncthreads();
  }
  if(t==0) lse[b]=sm[0]+logf(ssb[0]);
}

// ================= K5: out -= lse[b] (in place, float4) ====================
__global__ __launch_bounds__(256) void k_sub(float* __restrict__ out,
                                             const float* __restrict__ lse){
  const size_t i=(size_t)blockIdx.x*256+threadIdx.x;  // float4 index
  const int b=(int)((i*4)/VN);                         // VN%4==0: no row cross
  const float l=lse[b];
  float4* p=(float4*)out;
  float4 x=p[i];
  x.x-=l; x.y-=l; x.z-=l; x.w-=l;
  p[i]=x;
}

extern "C" void kernel_launch(void* const* d_in, const int* in_sizes, int n_in,
                              void* d_out, int out_size, void* d_ws, size_t ws_size,
                              hipStream_t stream){
  const float* emb    = (const float*)d_in[0];
  // d_in[1..6]: W1,W2,gru_* — dead code in the reference, never read
  const float* fcu_w  = (const float*)d_in[7];
  const float* fcv_w  = (const float*)d_in[8];
  const float* fcv_b  = (const float*)d_in[9];
  const float* fce_w  = (const float*)d_in[10];
  const float* fcsr_w = (const float*)d_in[11];
  const float* red_w  = (const float*)d_in[12];
  const float* red_b  = (const float*)d_in[13];
  const float* rec_w  = (const float*)d_in[14];
  const float* rec_b  = (const float*)d_in[15];
  const float* cde_w1 = (const float*)d_in[16];
  const float* cde_b1 = (const float*)d_in[17];
  const float* cde_w2 = (const float*)d_in[18];
  const float* cde_b2 = (const float*)d_in[19];
  const float* init_w = (const float*)d_in[20];
  const float* init_b = (const float*)d_in[21];
  // d_in[22]: w (edge weights) — dead code
  const float* times  = (const float*)d_in[23];
  const int* iid    = (const int*)d_in[24];
  // d_in[25..27]: src,dst,seg_ids — dead / implied by layout
  const int* last_nodes = (const int*)d_in[28];
  const int* embeds_ids = (const int*)d_in[29];
  float* out = (float*)d_out;

  float* ws  = (float*)d_ws;
  float* te  = ws;                    // B*D = 65,536 f
  float* sr  = te + (size_t)BB*DD;    // B*D = 65,536 f
  float* lse = sr + (size_t)BB*DD;    // B   =     512 f   (total 526 KB)

  k_cde   <<<BB/2, 512, 0, stream>>>(emb, embeds_ids, times, red_w, red_b,
                                     cde_w1, cde_b1, cde_w2, cde_b2,
                                     init_w, init_b, rec_w, rec_b, te);
  k_attn  <<<BB, 128, 0, stream>>>(emb, iid, last_nodes, fcu_w, fcv_w, fcv_b,
                                   fce_w, fcsr_w, te, sr);
  k_logits<<<dim3((VN+255)/256, 2), 256, 0, stream>>>(emb, sr, out);
  k_lse   <<<BB, 256, 0, stream>>>(out, lse);
  k_sub   <<<(int)(((size_t)BB*VN/4+255)/256), 256, 0, stream>>>(out, lse);
}

// Round 6
// 3333.627 us; speedup vs baseline: 1.3485x; 1.3485x over previous
//
#include <hip/hip_runtime.h>
#include <cstdint>

// Problem constants (from reference)
#define VN 100000   // vocab
#define DD 128      // D
#define BB 512      // batch
#define LL 20       // session length
#define TT 20       // time steps
#define HH 32       // H
#define CC 33       // C = H+1
#define NC (HH*CC)  // 1056
#define GG 4        // sessions per k_cde block

typedef unsigned int u32;

#define DEV static __device__ __forceinline__

DEV float tanh_fast(float x){ float e=__expf(2.f*x); return 1.f - 2.f/(e+1.f); }

// broadcast a lane's value wave-wide via v_readlane -> SGPR (folds into v_fma scalar src)
DEV float rdlane(float v, int l){
  return __int_as_float(__builtin_amdgcn_readlane(__float_as_int(v), l));
}

// ================= K1: fused knots + CDE RK4 scan (G=4, pure stream) =======
// Rounds 1-5 post-mortem: register-caching w2 is impossible (w2 = 135K floats
// vs 131K floats in the ENTIRE CU register file; allocator budget stuck at 128
// -> every >128-live design spilled; scratch footprint 33 MB >> L2 -> the
// 2.3-8.2 GB HBM FETCH was SCRATCH, not w2). This version: ZERO per-thread
// arrays, live set ~80 VGPR -> no scratch; w2 streamed from L2 every substage
// (L2-resident, 540 KB << 4 MB). G=4 sessions/block amortizes the stream over
// 4x the compute and halves per-XCD L2 demand vs G=2.
// 512 threads, 128 blocks. Thread (h=t>>4,q=t&15) owns rows h*33+q, h*33+16+q
// for all 4 sessions; c=32 tail rows via per-wave butterfly.
__global__ __launch_bounds__(512) void k_cde(
    const float* __restrict__ emb, const int* __restrict__ eids,
    const float* __restrict__ times,
    const float* __restrict__ red_w, const float* __restrict__ red_b,
    const float* __restrict__ w1, const float* __restrict__ b1,
    const float* __restrict__ w2, const float* __restrict__ b2,
    const float* __restrict__ iw, const float* __restrict__ ib,
    const float* __restrict__ rw, const float* __restrict__ rb,
    float* __restrict__ te){
  __shared__ float s_u[GG*TT*DD + 32*129]; // ph1: er(80*128)|rw(32*129); ph2: w1(128*33)
  __shared__ float s_X[GG*TT*CC];          // [g][t][c], persistent (10.6 KB)
  __shared__ float s_b1[DD];
  __shared__ float s_b2[NC];
  __shared__ float s_h1[GG*DD];            // [g][j]
  __shared__ float s_z[GG*HH], s_zs[GG*HH], s_ks[GG*HH], s_kp[GG*HH], s_kt[GG*HH];
  __shared__ float s_dx[GG*CC];
  const int t = threadIdx.x;
  const int b0 = blockIdx.x*GG;
  const int lane = t & 63;
  const int wv = t >> 6;                 // wave 0..7
  const int h  = t >> 4;                 // 0..31
  const int q  = t & 15;                 // 0..15
  float* s_er = s_u;
  float* s_rw = s_u + GG*TT*DD;          // phase1, rows padded to 129
  float* s_w1 = s_u;                     // phase2 alias, [j*33+hh]

  // ---- phase 1: knots X[g][t][:] (80 rows) ----
  for (int i=t;i<HH*DD;i+=512){ int hh=i>>7, d=i&127; s_rw[hh*129+d]=red_w[i]; }
  if (t<GG*TT){ int g=t/TT, tt2=t%TT; s_X[(g*TT+tt2)*CC]=times[(b0+g)*TT+tt2]; }
  for (int pi=t;pi<GG*TT*DD;pi+=512){ int r=pi>>7, e=pi&127;
      s_er[pi]=emb[(size_t)eids[b0*TT+r]*DD+e]; }
  __syncthreads();
  for (int task=t; task<GG*TT*HH; task+=512){  // 2560 tasks; 32-aligned groups
    int r=task>>5, hh=task&31;
    const float* wr=s_rw+hh*129;
    const float* er=s_er+(size_t)r*DD;
    float acc=red_b[hh];
    #pragma unroll 16
    for(int e=0;e<DD;e++) acc += er[e]*wr[e];
    float ssq=acc*acc;
    #pragma unroll
    for(int o=16;o>0;o>>=1) ssq+=__shfl_xor(ssq,o,32);
    s_X[r*CC+1+hh]=acc/(sqrtf(ssq)+1e-12f);   // fode = l2n(...) into X[...,1+h]
  }
  __syncthreads();                            // fode readers done; union free

  // ---- phase 2 weights: w1 (stride 33), b1, b2 ----
  for (int i=t;i<DD*HH;i+=512){ int j=i>>5, hh=i&31; s_w1[j*33+hh]=w1[i]; }
  if (t<DD) s_b1[t]=b1[t];
  for (int i=t;i<NC;i+=512) s_b2[i]=b2[i];
  // ---- z0 = X[:,0] @ init_w.T + init_b ----
  if (t<GG*HH){
    int g=t>>5, hh=t&31;
    float acc=ib[hh];
    const float* x0=s_X+(size_t)(g*TT)*CC;
    #pragma unroll
    for(int c=0;c<CC;c++) acc += x0[c]*iw[hh*CC+c];
    s_z[t]=acc; s_zs[t]=acc;
  }
  __syncthreads();   // w1/b1/b2/z0 ready

  const float4* r1 = (const float4*)(w2 + (size_t)(h*CC+q)*DD);
  const float4* r2 = (const float4*)(w2 + (size_t)(h*CC+16+q)*DD);
  const float* tr0 = w2 + (size_t)((4*wv+0)*CC+32)*DD;
  const float* tr1 = w2 + (size_t)((4*wv+1)*CC+32)*DD;
  const float* tr2 = w2 + (size_t)((4*wv+2)*CC+32)*DD;
  const float* tr3 = w2 + (size_t)((4*wv+3)*CC+32)*DD;
  const float bA = s_b2[h*CC+q];
  const float bB = s_b2[h*CC+16+q];

  for (int step=0; step<TT-1; step++){
    if (t<GG*CC){ int g=t/CC, c=t-g*CC;
      s_dx[t]=s_X[(g*TT+step+1)*CC+c]-s_X[(g*TT+step)*CC+c]; }
    for (int s=0;s<4;s++){
      // ---- stage A: h1[g][j] = relu(b1[j] + sum_h zs[g][h]*w1[j][h]) ----
      {
        const int g=t>>7, j=t&127;
        float zsv=s_zs[g*HH + (lane&31)];
        float acc=s_b1[j];
        const float* wj=s_w1+j*33;
        #pragma unroll
        for(int hh=0;hh<HH;hh++) acc += rdlane(zsv, hh)*wj[hh];
        s_h1[g*DD+j]=fmaxf(acc,0.f);
      }
      __syncthreads();   // sync_A: h1 + s_dx ready
      {
        // h1 fragments: lane holds h1[g][lane], h1[g][64+lane]
        const float hA0=s_h1[lane],      hB0=s_h1[64+lane];
        const float hA1=s_h1[DD+lane],   hB1=s_h1[DD+64+lane];
        const float hA2=s_h1[2*DD+lane], hB2=s_h1[2*DD+64+lane];
        const float hA3=s_h1[3*DD+lane], hB3=s_h1[3*DD+64+lane];
        // tail-row weights (L1-resident; issued early to hide latency)
        const float wt0=tr0[lane], wt1=tr0[64+lane];
        const float wt2=tr1[lane], wt3=tr1[64+lane];
        const float wt4=tr2[lane], wt5=tr2[64+lane];
        const float wt6=tr3[lane], wt7=tr3[64+lane];
        // ---- main rows: stream w2 from L2, broadcast h1 via readlane ----
        float aA0=0.f,aA1=0.f,aA2=0.f,aA3=0.f;
        float aB0=0.f,aB1=0.f,aB2=0.f,aB3=0.f;
        #pragma unroll
        for (int j4=0;j4<32;j4++){
          const float4 wa=r1[j4];
          const float4 wb=r2[j4];
          #pragma unroll
          for (int e=0;e<4;e++){
            const int jj=4*j4+e;
            const float wea = e==0?wa.x : e==1?wa.y : e==2?wa.z : wa.w;
            const float web = e==0?wb.x : e==1?wb.y : e==2?wb.z : wb.w;
            const float s0 = (jj<64)? rdlane(hA0,jj) : rdlane(hB0,jj-64);
            const float s1 = (jj<64)? rdlane(hA1,jj) : rdlane(hB1,jj-64);
            const float s2 = (jj<64)? rdlane(hA2,jj) : rdlane(hB2,jj-64);
            const float s3 = (jj<64)? rdlane(hA3,jj) : rdlane(hB3,jj-64);
            aA0 += s0*wea; aB0 += s0*web;
            aA1 += s1*wea; aB1 += s1*web;
            aA2 += s2*wea; aB2 += s2*web;
            aA3 += s3*wea; aB3 += s3*web;
          }
        }
        float k0 = tanh_fast(aA0+bA)*s_dx[q]      + tanh_fast(aB0+bB)*s_dx[16+q];
        float k1 = tanh_fast(aA1+bA)*s_dx[CC+q]   + tanh_fast(aB1+bB)*s_dx[CC+16+q];
        float k2 = tanh_fast(aA2+bA)*s_dx[2*CC+q] + tanh_fast(aB2+bB)*s_dx[2*CC+16+q];
        float k3 = tanh_fast(aA3+bA)*s_dx[3*CC+q] + tanh_fast(aB3+bB)*s_dx[3*CC+16+q];
        #pragma unroll
        for (int o=8;o>0;o>>=1){
          k0+=__shfl_xor(k0,o,16); k1+=__shfl_xor(k1,o,16);
          k2+=__shfl_xor(k2,o,16); k3+=__shfl_xor(k3,o,16);
        }
        if (q==0){ s_kp[h]=k0; s_kp[HH+h]=k1; s_kp[2*HH+h]=k2; s_kp[3*HH+h]=k3; }
        // ---- tail rows (c=32): per-wave butterfly, 4 rows x 4 sessions ----
        float p00=wt0*hA0+wt1*hB0, p01=wt0*hA1+wt1*hB1,
              p02=wt0*hA2+wt1*hB2, p03=wt0*hA3+wt1*hB3;
        float p10=wt2*hA0+wt3*hB0, p11=wt2*hA1+wt3*hB1,
              p12=wt2*hA2+wt3*hB2, p13=wt2*hA3+wt3*hB3;
        float p20=wt4*hA0+wt5*hB0, p21=wt4*hA1+wt5*hB1,
              p22=wt4*hA2+wt5*hB2, p23=wt4*hA3+wt5*hB3;
        float p30=wt6*hA0+wt7*hB0, p31=wt6*hA1+wt7*hB1,
              p32=wt6*hA2+wt7*hB2, p33=wt6*hA3+wt7*hB3;
        #pragma unroll
        for (int o=1;o<64;o<<=1){
          p00+=__shfl_xor(p00,o,64); p01+=__shfl_xor(p01,o,64);
          p02+=__shfl_xor(p02,o,64); p03+=__shfl_xor(p03,o,64);
          p10+=__shfl_xor(p10,o,64); p11+=__shfl_xor(p11,o,64);
          p12+=__shfl_xor(p12,o,64); p13+=__shfl_xor(p13,o,64);
          p20+=__shfl_xor(p20,o,64); p21+=__shfl_xor(p21,o,64);
          p22+=__shfl_xor(p22,o,64); p23+=__shfl_xor(p23,o,64);
          p30+=__shfl_xor(p30,o,64); p31+=__shfl_xor(p31,o,64);
          p32+=__shfl_xor(p32,o,64); p33+=__shfl_xor(p33,o,64);
        }
        if (lane==0){
          const float btl0=s_b2[(4*wv+0)*CC+32], btl1=s_b2[(4*wv+1)*CC+32];
          const float btl2=s_b2[(4*wv+2)*CC+32], btl3=s_b2[(4*wv+3)*CC+32];
          const float d0=s_dx[32], d1=s_dx[CC+32], d2=s_dx[2*CC+32], d3=s_dx[3*CC+32];
          s_kt[     4*wv+0]=tanh_fast(p00+btl0)*d0;
          s_kt[HH  +4*wv+0]=tanh_fast(p01+btl0)*d1;
          s_kt[2*HH+4*wv+0]=tanh_fast(p02+btl0)*d2;
          s_kt[3*HH+4*wv+0]=tanh_fast(p03+btl0)*d3;
          s_kt[     4*wv+1]=tanh_fast(p10+btl1)*d0;
          s_kt[HH  +4*wv+1]=tanh_fast(p11+btl1)*d1;
          s_kt[2*HH+4*wv+1]=tanh_fast(p12+btl1)*d2;
          s_kt[3*HH+4*wv+1]=tanh_fast(p13+btl1)*d3;
          s_kt[     4*wv+2]=tanh_fast(p20+btl2)*d0;
          s_kt[HH  +4*wv+2]=tanh_fast(p21+btl2)*d1;
          s_kt[2*HH+4*wv+2]=tanh_fast(p22+btl2)*d2;
          s_kt[3*HH+4*wv+2]=tanh_fast(p23+btl2)*d3;
          s_kt[     4*wv+3]=tanh_fast(p30+btl3)*d0;
          s_kt[HH  +4*wv+3]=tanh_fast(p31+btl3)*d1;
          s_kt[2*HH+4*wv+3]=tanh_fast(p32+btl3)*d2;
          s_kt[3*HH+4*wv+3]=tanh_fast(p33+btl3)*d3;
        }
      }
      __syncthreads();   // sync_B: kp/kt ready
      if (t<GG*HH){      // RK4 bookkeeping: one thread per (g,h)
        float k=s_kp[t]+s_kt[t];
        float zv=s_z[t];
        if(s==0){ s_ks[t]=k;        s_zs[t]=zv+0.5f*k; }
        else if(s==1){ s_ks[t]+=2.f*k; s_zs[t]=zv+0.5f*k; }
        else if(s==2){ s_ks[t]+=2.f*k; s_zs[t]=zv+k; }
        else { float zn=zv+(s_ks[t]+k)*(1.f/6.f); s_z[t]=zn; s_zs[t]=zn; }
      }
      __syncthreads();   // sync_C: zs ready for next substage
    }
  }
  // ---- epilogue: time_embeds = zT @ rec_w.T + rec_b (4g x 128d = 512) ----
  {
    const int g=t>>7, d=t&127;
    float acc=rb[d];
    const float* zz=s_z+g*HH;
    const float4* rv=(const float4*)(rw + (size_t)d*HH);
    #pragma unroll
    for(int jj=0;jj<8;jj++){
      float4 vv=rv[jj];
      acc += zz[4*jj]*vv.x + zz[4*jj+1]*vv.y + zz[4*jj+2]*vv.z + zz[4*jj+3]*vv.w;
    }
    te[(size_t)(b0+g)*DD+d]=acc;
  }
}

// ================= K2: attention readout + sr (featn recomputed) ===========
__global__ __launch_bounds__(128) void k_attn(
    const float* __restrict__ emb, const int* __restrict__ iid,
    const int* __restrict__ last_nodes,
    const float* __restrict__ fcu_w, const float* __restrict__ fcv_w,
    const float* __restrict__ fcv_b, const float* __restrict__ fce_w,
    const float* __restrict__ fcsr_w,
    const float* __restrict__ te, float* __restrict__ sr){
  __shared__ float s_fn[LL*DD];      // featn tile = x/||x||
  __shared__ float s_inv[LL];
  __shared__ float s_e[LL], s_alpha[LL], s_red[2], s_sg[DD], s_fl[DD];
  const int t=threadIdx.x, b=blockIdx.x;
  for(int p=t;p<LL*DD;p+=128){
    int r=p>>7, e=p&127;
    s_fn[p]=emb[(size_t)iid[b*LL+r]*DD+e];
  }
  __syncthreads();
  { int w=t>>6, lane=t&63;
    for(int r=w;r<LL;r+=2){
      float a=s_fn[r*DD+lane], c=s_fn[r*DD+lane+64];
      float s=a*a+c*c;
      #pragma unroll
      for(int o=32;o>0;o>>=1) s+=__shfl_xor(s,o,64);
      if(lane==0) s_inv[r]=1.f/sqrtf(s);
    }
  }
  __syncthreads();
  for(int p=t;p<LL*DD;p+=128) s_fn[p]*=s_inv[p>>7];
  __syncthreads();
  int lr=last_nodes[b]-b*LL; if(lr<0||lr>=LL) lr=LL-1;   // == L-1 by construction
  s_fl[t]=s_fn[lr*DD+t];
  __syncthreads();
  float fv;
  {
    float acc=fcv_b[t];
    const float* wvv=fcv_w + t*DD;
    #pragma unroll 8
    for(int j=0;j<DD;j++) acc += s_fl[j]*wvv[j];
    fv=acc;
  }
  const float fce=fce_w[t];
  const float* wu=fcu_w + t*DD;
  for(int n=0;n<LL;n++){
    float fu=0.f;
    #pragma unroll 8
    for(int j=0;j<DD;j++) fu += s_fn[n*DD+j]*wu[j];
    float sv = fce/(1.f+__expf(-(fu+fv)));   // sigmoid * fce_w[d]
    #pragma unroll
    for(int o=32;o>0;o>>=1) sv += __shfl_xor(sv,o,64);
    if((t&63)==0) s_red[t>>6]=sv;
    __syncthreads();
    if(t==0) s_e[n]=s_red[0]+s_red[1];
    __syncthreads();
  }
  if(t<64){ // softmax over the 20 session nodes
    float ev=(t<LL)? s_e[t] : -1e30f;
    float m=ev;
    #pragma unroll
    for(int o=32;o>0;o>>=1) m=fmaxf(m,__shfl_xor(m,o,64));
    float ex=(t<LL)? __expf(ev-m):0.f;
    float ssum=ex;
    #pragma unroll
    for(int o=32;o>0;o>>=1) ssum+=__shfl_xor(ssum,o,64);
    if(t<LL) s_alpha[t]=ex/ssum;
  }
  __syncthreads();
  float sg=0.f;
  for(int n=0;n<LL;n++) sg += s_alpha[n]*s_fn[n*DD+t];
  s_sg[t]=sg;
  __syncthreads();
  // sr = l2n([sr_l, sr_g] @ fcsr_w.T + te)
  float pre=te[(size_t)b*DD+t];
  const float* wsr=fcsr_w + t*2*DD;
  #pragma unroll 8
  for(int j=0;j<DD;j++) pre += s_fl[j]*wsr[j];
  #pragma unroll 8
  for(int j=0;j<DD;j++) pre += s_sg[j]*wsr[DD+j];
  float ss=pre*pre;
  #pragma unroll
  for(int o=32;o>0;o>>=1) ss+=__shfl_xor(ss,o,64);
  if((t&63)==0) s_red[t>>6]=ss;
  __syncthreads();
  float tot=s_red[0]+s_red[1];
  sr[(size_t)b*DD+t]=pre/(sqrtf(tot)+1e-12f);
}

// ================= K3: logits, loop-inverted (no per-thread row residency) ==
// Thread owns vocab column v and a 64-row b-tile of accumulators (acc[64],
// compile-time indexed -> registers). sr tile lives in LDS (broadcast reads:
// all lanes same address = conflict-free). emb row is re-read per b-tile from
// L2/L3 (emb 51 MB fits L3; 8x re-read ~ 400 MB ~ 40 us) instead of fighting
// the allocator for 128 resident floats (rounds 1-5 lesson).
#define BT 64
__global__ __launch_bounds__(256) void k_logits(
    const float* __restrict__ emb, const float* __restrict__ srr,
    float* __restrict__ out){
  __shared__ float s_sr[BT*DD];          // 32 KB
  const int tdx=threadIdx.x;
  const int btile=blockIdx.y;            // 0..7
  for (int i=tdx;i<BT*DD;i+=256) s_sr[i]=srr[(size_t)btile*BT*DD+i];
  __syncthreads();
  const int v=blockIdx.x*256+tdx;
  if (v>=VN) return;
  const float4* ev=(const float4*)(emb+(size_t)v*DD);
  const float4* sr4=(const float4*)s_sr;
  float acc[BT];
  #pragma unroll
  for (int b=0;b<BT;b++) acc[b]=0.f;
  float nrm=0.f;
  for (int j4=0;j4<32;j4++){             // rolled: 1 global b128 + 64 LDS b128
    const float4 e4=ev[j4];
    nrm += e4.x*e4.x+e4.y*e4.y+e4.z*e4.z+e4.w*e4.w;
    #pragma unroll
    for (int b=0;b<BT;b++){
      const float4 s4=sr4[b*32+j4];      // imm offset b*512, broadcast
      acc[b] += e4.x*s4.x+e4.y*s4.y+e4.z*s4.z+e4.w*s4.w;
    }
  }
  const float rn=12.f/(sqrtf(nrm)+1e-12f);
  #pragma unroll
  for (int b=0;b<BT;b++)
    out[(size_t)(btile*BT+b)*VN+v]=acc[b]*rn;
}

// ================= K4: per-row logsumexp over V (online, f32) ==============
__global__ __launch_bounds__(256) void k_lse(const float* __restrict__ out,
                                             float* __restrict__ lse){
  const int b=blockIdx.x, t=threadIdx.x;
  const float4* rp=(const float4*)(out + (size_t)b*VN);
  float m=-1e30f, s=0.f;
  for(int i=t;i<VN/4;i+=256){
    float4 x=rp[i];
    float mx=fmaxf(fmaxf(x.x,x.y),fmaxf(x.z,x.w));
    if(mx>m){ s=s*__expf(m-mx); m=mx; }
    s += __expf(x.x-m)+__expf(x.y-m)+__expf(x.z-m)+__expf(x.w-m);
  }
  __shared__ float sm[256], ssb[256];
  sm[t]=m; ssb[t]=s;
  __syncthreads();
  for(int o=128;o>0;o>>=1){
    if(t<o){
      float m1=sm[t], m2=sm[t+o], s1=ssb[t], s2=ssb[t+o];
      float mm=fmaxf(m1,m2);
      sm[t]=mm; ssb[t]=s1*__expf(m1-mm)+s2*__expf(m2-mm);
    }
    __syncthreads();
  }
  if(t==0) lse[b]=sm[0]+logf(ssb[0]);
}

// ================= K5: out -= lse[b] (in place, float4) ====================
__global__ __launch_bounds__(256) void k_sub(float* __restrict__ out,
                                             const float* __restrict__ lse){
  const size_t i=(size_t)blockIdx.x*256+threadIdx.x;  // float4 index
  const int b=(int)((i*4)/VN);                         // VN%4==0: no row cross
  const float l=lse[b];
  float4* p=(float4*)out;
  float4 x=p[i];
  x.x-=l; x.y-=l; x.z-=l; x.w-=l;
  p[i]=x;
}

extern "C" void kernel_launch(void* const* d_in, const int* in_sizes, int n_in,
                              void* d_out, int out_size, void* d_ws, size_t ws_size,
                              hipStream_t stream){
  const float* emb    = (const float*)d_in[0];
  // d_in[1..6]: W1,W2,gru_* — dead code in the reference, never read
  const float* fcu_w  = (const float*)d_in[7];
  const float* fcv_w  = (const float*)d_in[8];
  const float* fcv_b  = (const float*)d_in[9];
  const float* fce_w  = (const float*)d_in[10];
  const float* fcsr_w = (const float*)d_in[11];
  const float* red_w  = (const float*)d_in[12];
  const float* red_b  = (const float*)d_in[13];
  const float* rec_w  = (const float*)d_in[14];
  const float* rec_b  = (const float*)d_in[15];
  const float* cde_w1 = (const float*)d_in[16];
  const float* cde_b1 = (const float*)d_in[17];
  const float* cde_w2 = (const float*)d_in[18];
  const float* cde_b2 = (const float*)d_in[19];
  const float* init_w = (const float*)d_in[20];
  const float* init_b = (const float*)d_in[21];
  // d_in[22]: w (edge weights) — dead code
  const float* times  = (const float*)d_in[23];
  const int* iid    = (const int*)d_in[24];
  // d_in[25..27]: src,dst,seg_ids — dead / implied by layout
  const int* last_nodes = (const int*)d_in[28];
  const int* embeds_ids = (const int*)d_in[29];
  float* out = (float*)d_out;

  float* ws  = (float*)d_ws;
  float* te  = ws;                    // B*D = 65,536 f
  float* sr  = te + (size_t)BB*DD;    // B*D = 65,536 f
  float* lse = sr + (size_t)BB*DD;    // B   =     512 f   (total 526 KB)

  k_cde   <<<BB/GG, 512, 0, stream>>>(emb, embeds_ids, times, red_w, red_b,
                                      cde_w1, cde_b1, cde_w2, cde_b2,
                                      init_w, init_b, rec_w, rec_b, te);
  k_attn  <<<BB, 128, 0, stream>>>(emb, iid, last_nodes, fcu_w, fcv_w, fcv_b,
                                   fce_w, fcsr_w, te, sr);
  k_logits<<<dim3((VN+255)/256, BB/BT), 256, 0, stream>>>(emb, sr, out);
  k_lse   <<<BB, 256, 0, stream>>>(out, lse);
  k_sub   <<<(int)(((size_t)BB*VN/4+255)/256), 256, 0, stream>>>(out, lse);
}